// Round 14
// baseline (552.156 us; speedup 1.0000x reference)
//
#include <hip/hip_runtime.h>
#include <hip/hip_fp16.h>
#include <math.h>

constexpr float NEG_SLOPE = 0.2f;
constexpr float EPS_BN = 1e-5f;
constexpr float EPS_SM = 1e-16f;

typedef _Float16 half8 __attribute__((ext_vector_type(8)));
typedef float f32x4 __attribute__((ext_vector_type(4)));

__device__ __forceinline__ float lrelu(float x){ return x >= 0.f ? x : NEG_SLOPE * x; }

typedef const __attribute__((address_space(1))) unsigned int* gas_u32;
typedef __attribute__((address_space(3))) unsigned int* las_u32;

__device__ __forceinline__ void llds16(const _Float16* g, _Float16* l){
  __builtin_amdgcn_global_load_lds((gas_u32)(const void*)g, (las_u32)(void*)l, 16, 0, 0);
}

// ---------------- prep0: cnt=1 (self-loop) + zero bn/tick ----------------
__global__ void k_prep0(int* cnt, int n, float* bn, int* tick){
  int t = blockIdx.x * blockDim.x + threadIdx.x;
  if (t < n) cnt[t] = 1;
  if (t < 256) bn[t] = 0.f;
  if (t < 4) tick[t] = 0;
}

// ---------------- prep1: x->fp16 + weight fp16-transpose + edge count ----------------
__global__ void k_prep1(const float* __restrict__ x, _Float16* __restrict__ xh, int n8,
                        const int* __restrict__ ei, int E, int* __restrict__ cnt,
                        const float* __restrict__ W0, const float* __restrict__ W1,
                        const float* __restrict__ W2, _Float16* __restrict__ Wt0,
                        _Float16* __restrict__ Wt1, _Float16* __restrict__ Wt2){
  int t = blockIdx.x * blockDim.x + threadIdx.x;
  if (t < n8){
    const float4* p = (const float4*)(x + (size_t)t * 8);
    float4 v0 = p[0], v1 = p[1];
    half8 h = {(_Float16)v0.x, (_Float16)v0.y, (_Float16)v0.z, (_Float16)v0.w,
               (_Float16)v1.x, (_Float16)v1.y, (_Float16)v1.z, (_Float16)v1.w};
    *(half8*)(xh + (size_t)t * 8) = h;
  }
  if (t < E) atomicAdd(&cnt[ei[E + t]], 1);
  if (t < 65536){
    int c = t & 255, k = t >> 8;
    Wt0[(size_t)c * 256 + k] = (_Float16)W0[(size_t)k * 256 + c];
  } else if (t < 81920){
    int u = t - 65536; int c = u & 255, k = u >> 8;
    Wt1[(size_t)c * 64 + k] = (_Float16)W1[(size_t)k * 256 + c];
  } else if (t < 98304){
    int u = t - 81920; int c = u & 255, k = u >> 8;
    Wt2[(size_t)c * 64 + k] = (_Float16)W2[(size_t)k * 256 + c];
  }
}

// ---------------- CSR scans ----------------
__global__ __launch_bounds__(256) void k_bsumscan(const int* __restrict__ cnt, int n, int chunk,
                                                  int* __restrict__ part, int* __restrict__ ptr,
                                                  int* __restrict__ tick){
  __shared__ int s[256];
  __shared__ int amLast;
  int b = blockIdx.x, t = threadIdx.x;
  int lo = b * chunk, hi = min(n, lo + chunk);
  int v = 0;
  for (int i = lo + t; i < hi; i += 256) v += cnt[i];
  s[t] = v;
  __syncthreads();
  #pragma unroll
  for (int off = 128; off > 0; off >>= 1){
    if (t < off) s[t] += s[t + off];
    __syncthreads();
  }
  if (t == 0) part[b] = s[0];
  __threadfence();
  if (t == 0) amLast = (atomicAdd(tick, 1) == (int)gridDim.x - 1) ? 1 : 0;
  __syncthreads();
  if (amLast){
    int pv = atomicAdd(&part[t], 0);
    s[t] = pv;
    __syncthreads();
    #pragma unroll
    for (int off = 1; off < 256; off <<= 1){
      int u = (t >= off) ? s[t - off] : 0;
      __syncthreads();
      s[t] += u;
      __syncthreads();
    }
    part[t] = s[t] - pv;
    if (t == 255) ptr[n] = s[255];
  }
}

__global__ __launch_bounds__(256) void k_localscan(const int* __restrict__ cnt, const int* __restrict__ part,
                                                   int n, int chunk, int* __restrict__ ptr,
                                                   int* __restrict__ cursor, int* __restrict__ csr_src){
  __shared__ int s[256];
  int b = blockIdx.x, t = threadIdx.x;
  int i = b * chunk + t;
  int v = (t < chunk && i < n) ? cnt[i] : 0;
  s[t] = v;
  __syncthreads();
  #pragma unroll
  for (int off = 1; off < 256; off <<= 1){
    int u = (t >= off) ? s[t - off] : 0;
    __syncthreads();
    s[t] += u;
    __syncthreads();
  }
  if (t < chunk && i < n){
    int ex = part[b] + s[t] - v;
    ptr[i] = ex;
    cursor[i] = ex;
    csr_src[ex + v - 1] = i;     // self-loop in last slot
  }
}

// ---------------- MFMA GEMM: 128 rows x 256 cols per block; wave w = head w ----------------
// LAYER 0 FUSED with csr fill: blocks >= gemmBlocks run the edge scatter.
// hb layout PERMUTED: hb[row][w*64 + lm*4 + j].
template<int LAYER>
__global__ __launch_bounds__(256, 2) void k_gemm(const _Float16* __restrict__ Xh,
    const float* __restrict__ Xf,
    const _Float16* __restrict__ Wt, const float* __restrict__ a_s, const float* __restrict__ a_d,
    __half* __restrict__ hb, float* __restrict__ al, float* __restrict__ ar, int nrows,
    const float* __restrict__ scale, const float* __restrict__ shift,
    const int* __restrict__ ei, int E, int* __restrict__ cursor, int* __restrict__ csr_src,
    int gemmBlocks){
  constexpr int K = (LAYER == 0) ? 256 : 64;
  if (LAYER == 0 && (int)blockIdx.x >= gemmBlocks){
    int stride = ((int)gridDim.x - gemmBlocks) * 256;
    for (int e = ((int)blockIdx.x - gemmBlocks) * 256 + (int)threadIdx.x; e < E; e += stride){
      int src = ei[e], dst = ei[E + e];
      int slot = atomicAdd(&cursor[dst], 1);
      csr_src[slot] = src;
    }
    return;
  }
  __shared__ _Float16 Alds[4][129][8];
  __shared__ _Float16 Blds[4][257][8];
  int tid = threadIdx.x;
  int m0 = blockIdx.x * 128;
  int w = tid >> 6, l = tid & 63;
  int lm = l & 15, lq = l >> 4;
  f32x4 acc[8][4] = {};

  for (int k0 = 0; k0 < K; k0 += 32){
    if (LAYER == 0){
      #pragma unroll
      for (int it = 0; it < 2; it++){
        int gr = m0 + it * 64 + l;
        if (gr < nrows)
          llds16(Xh + (size_t)gr * K + k0 + w * 8, &Alds[w][it * 64][0]);
      }
    } else {
      float4 sc0 = *(const float4*)(scale + k0 + w * 8);
      float4 sc1 = *(const float4*)(scale + k0 + w * 8 + 4);
      float4 sh0 = *(const float4*)(shift + k0 + w * 8);
      float4 sh1 = *(const float4*)(shift + k0 + w * 8 + 4);
      #pragma unroll
      for (int it = 0; it < 2; it++){
        int row = it * 64 + l;
        int gr = m0 + row;
        float4 v0 = make_float4(0,0,0,0), v1 = make_float4(0,0,0,0);
        if (gr < nrows){
          v0 = *(const float4*)(Xf + (size_t)gr * K + k0 + w * 8);
          v1 = *(const float4*)(Xf + (size_t)gr * K + k0 + w * 8 + 4);
        }
        v0.x = fmaxf(fmaf(v0.x, sc0.x, sh0.x), 0.f);
        v0.y = fmaxf(fmaf(v0.y, sc0.y, sh0.y), 0.f);
        v0.z = fmaxf(fmaf(v0.z, sc0.z, sh0.z), 0.f);
        v0.w = fmaxf(fmaf(v0.w, sc0.w, sh0.w), 0.f);
        v1.x = fmaxf(fmaf(v1.x, sc1.x, sh1.x), 0.f);
        v1.y = fmaxf(fmaf(v1.y, sc1.y, sh1.y), 0.f);
        v1.z = fmaxf(fmaf(v1.z, sc1.z, sh1.z), 0.f);
        v1.w = fmaxf(fmaf(v1.w, sc1.w, sh1.w), 0.f);
        half8 h = {(_Float16)v0.x, (_Float16)v0.y, (_Float16)v0.z, (_Float16)v0.w,
                   (_Float16)v1.x, (_Float16)v1.y, (_Float16)v1.z, (_Float16)v1.w};
        *(half8*)&Alds[w][row][0] = h;
      }
    }
    #pragma unroll
    for (int it = 0; it < 4; it++){
      int col = it * 64 + l;
      llds16(Wt + (size_t)col * K + k0 + w * 8, &Blds[w][it * 64][0]);
    }
    __syncthreads();
    half8 af[8];
    #pragma unroll
    for (int mf = 0; mf < 8; mf++) af[mf] = *(const half8*)&Alds[lq][mf * 16 + lm][0];
    #pragma unroll
    for (int j = 0; j < 4; j++){
      half8 bf = *(const half8*)&Blds[lq][(w * 4 + j) * 16 + lm][0];
      #pragma unroll
      for (int mf = 0; mf < 8; mf++)
        acc[mf][j] = __builtin_amdgcn_mfma_f32_16x16x32_f16(af[mf], bf, acc[mf][j], 0, 0, 0);
    }
    __syncthreads();
  }

  float asv[4], adv[4];
  #pragma unroll
  for (int j = 0; j < 4; j++){
    asv[j] = a_s[w * 64 + j * 16 + lm];
    adv[j] = a_d[w * 64 + j * 16 + lm];
  }
  #pragma unroll
  for (int mf = 0; mf < 8; mf++){
    #pragma unroll
    for (int reg = 0; reg < 4; reg++){
      float sl = acc[mf][0][reg] * asv[0] + acc[mf][1][reg] * asv[1]
               + acc[mf][2][reg] * asv[2] + acc[mf][3][reg] * asv[3];
      float sr = acc[mf][0][reg] * adv[0] + acc[mf][1][reg] * adv[1]
               + acc[mf][2][reg] * adv[2] + acc[mf][3][reg] * adv[3];
      #pragma unroll
      for (int off = 1; off < 16; off <<= 1){
        sl += __shfl_xor(sl, off);
        sr += __shfl_xor(sr, off);
      }
      int row = m0 + mf * 16 + lq * 4 + reg;
      if (lm == 0 && row < nrows){
        al[(size_t)row * 4 + w] = sl;
        ar[(size_t)row * 4 + w] = sr;
      }
      if (row < nrows){
        ushort4 pk;
        pk.x = __half_as_ushort(__float2half(acc[mf][0][reg]));
        pk.y = __half_as_ushort(__float2half(acc[mf][1][reg]));
        pk.z = __half_as_ushort(__float2half(acc[mf][2][reg]));
        pk.w = __half_as_ushort(__float2half(acc[mf][3][reg]));
        *(ushort4*)(hb + (size_t)row * 256 + w * 64 + lm * 4) = pk;
      }
    }
  }
}

// ---------------- per-node softmax + aggregate (wave per node) ----------------
__global__ __launch_bounds__(256) void k_node(const int* __restrict__ ptr,
    const int* __restrict__ csr, const __half* __restrict__ hb,
    const float* __restrict__ al, const float* __restrict__ ar,
    const float* __restrict__ bias, float* __restrict__ out, int N){
  __shared__ float4 wsm[4][64];
  __shared__ int    ssm[4][64];
  int n = (blockIdx.x * blockDim.x + threadIdx.x) >> 6;
  int lane = threadIdx.x & 63;
  int wv = threadIdx.x >> 6;
  if (n >= N) return;
  int beg = ptr[n], end = ptr[n + 1];
  int deg = end - beg;
  float4 arv = *(const float4*)(ar + (size_t)n * 4);

  if (deg <= 64){
    int idx = beg + lane;
    bool act = idx < end;
    int mye = act ? csr[idx] : 0;
    float e0 = -1e30f, e1 = -1e30f, e2 = -1e30f, e3 = -1e30f;
    if (act){
      float4 av = *(const float4*)((const char*)al + ((unsigned)mye << 4));
      e0 = lrelu(av.x + arv.x); e1 = lrelu(av.y + arv.y);
      e2 = lrelu(av.z + arv.z); e3 = lrelu(av.w + arv.w);
    }
    float m0 = e0, m1 = e1, m2 = e2, m3 = e3;
    #pragma unroll
    for (int off = 32; off > 0; off >>= 1){
      m0 = fmaxf(m0, __shfl_xor(m0, off));
      m1 = fmaxf(m1, __shfl_xor(m1, off));
      m2 = fmaxf(m2, __shfl_xor(m2, off));
      m3 = fmaxf(m3, __shfl_xor(m3, off));
    }
    float w0 = __expf(e0 - m0), w1 = __expf(e1 - m1);
    float w2 = __expf(e2 - m2), w3 = __expf(e3 - m3);
    float d0 = w0, d1 = w1, d2 = w2, d3 = w3;
    #pragma unroll
    for (int off = 32; off > 0; off >>= 1){
      d0 += __shfl_xor(d0, off);
      d1 += __shfl_xor(d1, off);
      d2 += __shfl_xor(d2, off);
      d3 += __shfl_xor(d3, off);
    }
    wsm[wv][lane] = make_float4(w0 / (d0 + EPS_SM), w1 / (d1 + EPS_SM),
                                w2 / (d2 + EPS_SM), w3 / (d3 + EPS_SM));
    ssm[wv][lane] = mye;
    __builtin_amdgcn_wave_barrier();

    int eh = lane >> 5;
    int hd = (lane >> 3) & 3;
    int c8 = lane & 7;
    unsigned choff = (unsigned)(hd * 128 + c8 * 16);
    const float* wbase = (const float*)&wsm[wv][0];
    float a0=0.f,a1=0.f,a2=0.f,a3=0.f,a4=0.f,a5=0.f,a6=0.f,a7=0.f;
    #pragma unroll 4
    for (int j = 0; j < deg; j += 2){
      int je = j + eh;
      int s = ssm[wv][je];
      float w = wbase[je * 4 + hd];
      int4 q = *(const int4*)((const char*)hb + (((unsigned)s << 9) + choff));
      const __half2* h2 = (const __half2*)&q;
      float2 f0 = __half22float2(h2[0]);
      float2 f1 = __half22float2(h2[1]);
      float2 f2 = __half22float2(h2[2]);
      float2 f3 = __half22float2(h2[3]);
      a0 = fmaf(f0.x, w, a0); a1 = fmaf(f0.y, w, a1);
      a2 = fmaf(f1.x, w, a2); a3 = fmaf(f1.y, w, a3);
      a4 = fmaf(f2.x, w, a4); a5 = fmaf(f2.y, w, a5);
      a6 = fmaf(f3.x, w, a6); a7 = fmaf(f3.y, w, a7);
    }
    #pragma unroll
    for (int off = 32; off >= 8; off >>= 1){
      a0 += __shfl_xor(a0, off); a1 += __shfl_xor(a1, off);
      a2 += __shfl_xor(a2, off); a3 += __shfl_xor(a3, off);
      a4 += __shfl_xor(a4, off); a5 += __shfl_xor(a5, off);
      a6 += __shfl_xor(a6, off); a7 += __shfl_xor(a7, off);
    }
    if (lane < 8){
      float* op = out + (size_t)n * 64 + c8 * 2;
      float2 b0 = *(const float2*)(bias + 0 * 16 + c8 * 2);
      float2 b1 = *(const float2*)(bias + 1 * 16 + c8 * 2);
      float2 b2 = *(const float2*)(bias + 2 * 16 + c8 * 2);
      float2 b3 = *(const float2*)(bias + 3 * 16 + c8 * 2);
      *(float2*)(op + 0)  = make_float2(a0 * 0.25f + b0.x, a4 * 0.25f + b0.y);
      *(float2*)(op + 16) = make_float2(a1 * 0.25f + b1.x, a5 * 0.25f + b1.y);
      *(float2*)(op + 32) = make_float2(a2 * 0.25f + b2.x, a6 * 0.25f + b2.y);
      *(float2*)(op + 48) = make_float2(a3 * 0.25f + b3.x, a7 * 0.25f + b3.y);
    }
  } else {
    int hd = lane >> 4;
    int t = lane & 15;
    const __half* hbase = hb + hd * 64 + t * 4;
    float ax = 0.f, ay = 0.f, az = 0.f, aw = 0.f;
    float m0 = -1e30f, m1 = -1e30f, m2 = -1e30f, m3 = -1e30f;
    for (int i = beg + lane; i < end; i += 64){
      int s = csr[i];
      float4 av = *(const float4*)(al + (size_t)s * 4);
      m0 = fmaxf(m0, lrelu(av.x + arv.x));
      m1 = fmaxf(m1, lrelu(av.y + arv.y));
      m2 = fmaxf(m2, lrelu(av.z + arv.z));
      m3 = fmaxf(m3, lrelu(av.w + arv.w));
    }
    #pragma unroll
    for (int off = 32; off > 0; off >>= 1){
      m0 = fmaxf(m0, __shfl_xor(m0, off));
      m1 = fmaxf(m1, __shfl_xor(m1, off));
      m2 = fmaxf(m2, __shfl_xor(m2, off));
      m3 = fmaxf(m3, __shfl_xor(m3, off));
    }
    float d0 = 0.f, d1 = 0.f, d2 = 0.f, d3 = 0.f;
    for (int i = beg + lane; i < end; i += 64){
      int s = csr[i];
      float4 av = *(const float4*)(al + (size_t)s * 4);
      d0 += __expf(lrelu(av.x + arv.x) - m0);
      d1 += __expf(lrelu(av.y + arv.y) - m1);
      d2 += __expf(lrelu(av.z + arv.z) - m2);
      d3 += __expf(lrelu(av.w + arv.w) - m3);
    }
    #pragma unroll
    for (int off = 32; off > 0; off >>= 1){
      d0 += __shfl_xor(d0, off);
      d1 += __shfl_xor(d1, off);
      d2 += __shfl_xor(d2, off);
      d3 += __shfl_xor(d3, off);
    }
    float i0 = 1.f / (d0 + EPS_SM), i1 = 1.f / (d1 + EPS_SM);
    float i2 = 1.f / (d2 + EPS_SM), i3 = 1.f / (d3 + EPS_SM);
    float arh = hd == 0 ? arv.x : hd == 1 ? arv.y : hd == 2 ? arv.z : arv.w;
    float mh  = hd == 0 ? m0 : hd == 1 ? m1 : hd == 2 ? m2 : m3;
    float ih  = hd == 0 ? i0 : hd == 1 ? i1 : hd == 2 ? i2 : i3;
    for (int i = beg; i < end; i++){
      int s = csr[i];
      float w = __expf(lrelu(al[(size_t)s * 4 + hd] + arh) - mh) * ih;
      ushort4 u = *(const ushort4*)(hbase + (size_t)s * 256);
      ax = fmaf(__half2float(__ushort_as_half(u.x)), w, ax);
      ay = fmaf(__half2float(__ushort_as_half(u.y)), w, ay);
      az = fmaf(__half2float(__ushort_as_half(u.z)), w, az);
      aw = fmaf(__half2float(__ushort_as_half(u.w)), w, aw);
    }
    #pragma unroll
    for (int off = 16; off <= 32; off <<= 1){
      ax += __shfl_xor(ax, off);
      ay += __shfl_xor(ay, off);
      az += __shfl_xor(az, off);
      aw += __shfl_xor(aw, off);
    }
    if (lane < 16){
      float* op = out + (size_t)n * 64;
      op[t]      = ax * 0.25f + bias[t];
      op[16 + t] = ay * 0.25f + bias[16 + t];
      op[32 + t] = az * 0.25f + bias[32 + t];
      op[48 + t] = aw * 0.25f + bias[48 + t];
    }
  }
}

// ---------------- BatchNorm stats + fused finalize -> scale/shift ----------------
__global__ __launch_bounds__(256) void k_bnstats(const float* __restrict__ x, int N,
                                                 float* __restrict__ gsum, float* __restrict__ gsq,
                                                 int* __restrict__ tick,
                                                 const float* __restrict__ g, const float* __restrict__ be,
                                                 float* __restrict__ scale, float* __restrict__ shift){
  int c = threadIdx.x & 63;
  int rg = threadIdx.x >> 6;
  float s = 0.f, q = 0.f;
  for (int r = blockIdx.x * 4 + rg; r < N; r += gridDim.x * 4){
    float v = x[(size_t)r * 64 + c];
    s += v; q += v * v;
  }
  __shared__ float ls[4][64], lq[4][64];
  __shared__ int amLast;
  ls[rg][c] = s; lq[rg][c] = q;
  __syncthreads();
  if (rg == 0){
    s = ls[0][c] + ls[1][c] + ls[2][c] + ls[3][c];
    q = lq[0][c] + lq[1][c] + lq[2][c] + lq[3][c];
    atomicAdd(&gsum[c], s);
    atomicAdd(&gsq[c], q);
  }
  __threadfence();
  if (threadIdx.x == 0)
    amLast = (atomicAdd(tick, 1) == (int)gridDim.x - 1) ? 1 : 0;
  __syncthreads();
  if (amLast && threadIdx.x < 64){
    float gs = atomicAdd(&gsum[c], 0.f);
    float gq = atomicAdd(&gsq[c], 0.f);
    float m = gs / (float)N;
    float v = gq / (float)N - m * m;
    float sc = g[c] * rsqrtf(v + EPS_BN);
    scale[c] = sc;
    shift[c] = be[c] - m * sc;
  }
}

// ---------------- launcher ----------------
extern "C" void kernel_launch(void* const* d_in, const int* in_sizes, int n_in,
                              void* d_out, int out_size, void* d_ws, size_t ws_size,
                              hipStream_t stream){
  const float* x  = (const float*)d_in[0];
  const int*   ei = (const int*)d_in[1];
  const float* W[3]  = {(const float*)d_in[2], (const float*)d_in[6],  (const float*)d_in[10]};
  const float* AS[3] = {(const float*)d_in[3], (const float*)d_in[7],  (const float*)d_in[11]};
  const float* AD[3] = {(const float*)d_in[4], (const float*)d_in[8],  (const float*)d_in[12]};
  const float* BI[3] = {(const float*)d_in[5], (const float*)d_in[9],  (const float*)d_in[13]};
  const float* G[2]  = {(const float*)d_in[14], (const float*)d_in[16]};
  const float* BE[2] = {(const float*)d_in[15], (const float*)d_in[17]};
  const int N = in_sizes[0] / 256;
  const int E = in_sizes[1] / 2;
  const int EN = E + N;

  char* wsb = (char*)d_ws;
  size_t off = 0;
  auto alloc = [&](size_t bytes) -> char* {
    char* p = wsb + off;
    off = (off + bytes + 255) & ~(size_t)255;
    return p;
  };
  int* cnt      = (int*)alloc((size_t)N * 4);
  int* cursor   = (int*)alloc((size_t)N * 4);
  int* rowptr   = (int*)alloc((size_t)(N + 1) * 4);
  int* part     = (int*)alloc(256 * 4);
  int* csr      = (int*)alloc((size_t)EN * 4);
  _Float16* xh  = (_Float16*)alloc((size_t)N * 256 * 2);
  _Float16* Wt0 = (_Float16*)alloc((size_t)256 * 256 * 2);
  _Float16* Wt1 = (_Float16*)alloc((size_t)64 * 256 * 2);
  _Float16* Wt2 = (_Float16*)alloc((size_t)64 * 256 * 2);
  __half* hb    = (__half*)alloc((size_t)N * 256 * 2);
  float* al     = (float*)alloc((size_t)N * 4 * 4);
  float* ar     = (float*)alloc((size_t)N * 4 * 4);
  float* bufA   = (float*)alloc((size_t)N * 64 * 4);
  float* bn     = (float*)alloc(256 * 4);
  int*   tick   = (int*)alloc(4 * 4);
  float* murs   = (float*)alloc(128 * 4);   // scale[64], shift[64]

  const int chunk = (N + 255) / 256;
  const int n8 = N * 32;
  const int nodeGrid = (N + 3) / 4;

  k_prep0<<<(N + 255) / 256, 256, 0, stream>>>(cnt, N, bn, tick);
  k_prep1<<<(n8 + 255) / 256, 256, 0, stream>>>(x, xh, n8, ei, E, cnt,
                                                W[0], W[1], W[2], Wt0, Wt1, Wt2);
  k_bsumscan<<<256, 256, 0, stream>>>(cnt, N, chunk, part, rowptr, tick + 2);
  k_localscan<<<256, 256, 0, stream>>>(cnt, part, N, chunk, rowptr, cursor, csr);

  int gemmGrid = (N + 127) / 128;
  const int FILLB = 1216;   // ~2.6 grid-stride rounds over E; latency-parallel fill
  // layer 0: gemm fused with csr fill
  k_gemm<0><<<gemmGrid + FILLB, 256, 0, stream>>>(xh, nullptr, Wt0, AS[0], AD[0], hb, al, ar, N,
                                                  nullptr, nullptr, ei, E, cursor, csr, gemmGrid);
  k_node<<<nodeGrid, 256, 0, stream>>>(rowptr, csr, hb, al, ar, BI[0], bufA, N);
  k_bnstats<<<128, 256, 0, stream>>>(bufA, N, bn, bn + 64, tick, G[0], BE[0], murs, murs + 64);
  // layer 1
  k_gemm<1><<<gemmGrid, 256, 0, stream>>>(nullptr, bufA, Wt1, AS[1], AD[1], hb, al, ar, N,
                                          murs, murs + 64, nullptr, 0, nullptr, nullptr, gemmGrid);
  k_node<<<nodeGrid, 256, 0, stream>>>(rowptr, csr, hb, al, ar, BI[1], bufA, N);
  k_bnstats<<<128, 256, 0, stream>>>(bufA, N, bn + 128, bn + 192, tick + 1, G[1], BE[1], murs, murs + 64);
  // layer 2
  k_gemm<2><<<gemmGrid, 256, 0, stream>>>(nullptr, bufA, Wt2, AS[2], AD[2], hb, al, ar, N,
                                          murs, murs + 64, nullptr, 0, nullptr, nullptr, gemmGrid);
  k_node<<<nodeGrid, 256, 0, stream>>>(rowptr, csr, hb, al, ar, BI[2], (float*)d_out, N);
}

// Round 15
// 542.728 us; speedup vs baseline: 1.0174x; 1.0174x over previous
//
#include <hip/hip_runtime.h>
#include <hip/hip_fp16.h>
#include <math.h>

constexpr float NEG_SLOPE = 0.2f;
constexpr float EPS_BN = 1e-5f;
constexpr float EPS_SM = 1e-16f;

typedef _Float16 half8 __attribute__((ext_vector_type(8)));
typedef float f32x4 __attribute__((ext_vector_type(4)));

__device__ __forceinline__ float lrelu(float x){ return x >= 0.f ? x : NEG_SLOPE * x; }

typedef const __attribute__((address_space(1))) unsigned int* gas_u32;
typedef __attribute__((address_space(3))) unsigned int* las_u32;

__device__ __forceinline__ void llds16(const _Float16* g, _Float16* l){
  __builtin_amdgcn_global_load_lds((gas_u32)(const void*)g, (las_u32)(void*)l, 16, 0, 0);
}

// ---------------- prep0: cnt=1 (self-loop) + zero bn/tick ----------------
__global__ void k_prep0(int* cnt, int n, float* bn, int* tick){
  int t = blockIdx.x * blockDim.x + threadIdx.x;
  if (t < n) cnt[t] = 1;
  if (t < 256) bn[t] = 0.f;
  if (t < 4) tick[t] = 0;
}

// ---------------- prep1: x->fp16 + weight fp16-transpose + edge count ----------------
__global__ void k_prep1(const float* __restrict__ x, _Float16* __restrict__ xh, int n8,
                        const int* __restrict__ ei, int E, int* __restrict__ cnt,
                        const float* __restrict__ W0, const float* __restrict__ W1,
                        const float* __restrict__ W2, _Float16* __restrict__ Wt0,
                        _Float16* __restrict__ Wt1, _Float16* __restrict__ Wt2){
  int t = blockIdx.x * blockDim.x + threadIdx.x;
  if (t < n8){
    const float4* p = (const float4*)(x + (size_t)t * 8);
    float4 v0 = p[0], v1 = p[1];
    half8 h = {(_Float16)v0.x, (_Float16)v0.y, (_Float16)v0.z, (_Float16)v0.w,
               (_Float16)v1.x, (_Float16)v1.y, (_Float16)v1.z, (_Float16)v1.w};
    *(half8*)(xh + (size_t)t * 8) = h;
  }
  if (t < E) atomicAdd(&cnt[ei[E + t]], 1);
  if (t < 65536){
    int c = t & 255, k = t >> 8;
    Wt0[(size_t)c * 256 + k] = (_Float16)W0[(size_t)k * 256 + c];
  } else if (t < 81920){
    int u = t - 65536; int c = u & 255, k = u >> 8;
    Wt1[(size_t)c * 64 + k] = (_Float16)W1[(size_t)k * 256 + c];
  } else if (t < 98304){
    int u = t - 81920; int c = u & 255, k = u >> 8;
    Wt2[(size_t)c * 64 + k] = (_Float16)W2[(size_t)k * 256 + c];
  }
}

// ---------------- CSR scans ----------------
__global__ __launch_bounds__(256) void k_bsumscan(const int* __restrict__ cnt, int n, int chunk,
                                                  int* __restrict__ part, int* __restrict__ ptr,
                                                  int* __restrict__ tick){
  __shared__ int s[256];
  __shared__ int amLast;
  int b = blockIdx.x, t = threadIdx.x;
  int lo = b * chunk, hi = min(n, lo + chunk);
  int v = 0;
  for (int i = lo + t; i < hi; i += 256) v += cnt[i];
  s[t] = v;
  __syncthreads();
  #pragma unroll
  for (int off = 128; off > 0; off >>= 1){
    if (t < off) s[t] += s[t + off];
    __syncthreads();
  }
  if (t == 0) part[b] = s[0];
  __threadfence();
  if (t == 0) amLast = (atomicAdd(tick, 1) == (int)gridDim.x - 1) ? 1 : 0;
  __syncthreads();
  if (amLast){
    int pv = atomicAdd(&part[t], 0);
    s[t] = pv;
    __syncthreads();
    #pragma unroll
    for (int off = 1; off < 256; off <<= 1){
      int u = (t >= off) ? s[t - off] : 0;
      __syncthreads();
      s[t] += u;
      __syncthreads();
    }
    part[t] = s[t] - pv;
    if (t == 255) ptr[n] = s[255];
  }
}

__global__ __launch_bounds__(256) void k_localscan(const int* __restrict__ cnt, const int* __restrict__ part,
                                                   int n, int chunk, int* __restrict__ ptr,
                                                   int* __restrict__ cursor, int* __restrict__ csr_src){
  __shared__ int s[256];
  int b = blockIdx.x, t = threadIdx.x;
  int i = b * chunk + t;
  int v = (t < chunk && i < n) ? cnt[i] : 0;
  s[t] = v;
  __syncthreads();
  #pragma unroll
  for (int off = 1; off < 256; off <<= 1){
    int u = (t >= off) ? s[t - off] : 0;
    __syncthreads();
    s[t] += u;
    __syncthreads();
  }
  if (t < chunk && i < n){
    int ex = part[b] + s[t] - v;
    ptr[i] = ex;
    cursor[i] = ex;
    csr_src[ex + v - 1] = i;     // self-loop in last slot
  }
}

// ---------------- MFMA GEMM: 128 rows x 256 cols per block; wave w = head w ----------------
// LAYER 0 FUSED with XCD-BINNED csr fill: fill block only handles dst range of its
// (heuristic) XCD so each csr/cursor cache line is dirtied in ONE L2 only.
// hb layout PERMUTED: hb[row][w*64 + lm*4 + j].
template<int LAYER>
__global__ __launch_bounds__(256, 2) void k_gemm(const _Float16* __restrict__ Xh,
    const float* __restrict__ Xf,
    const _Float16* __restrict__ Wt, const float* __restrict__ a_s, const float* __restrict__ a_d,
    __half* __restrict__ hb, float* __restrict__ al, float* __restrict__ ar, int nrows,
    const float* __restrict__ scale, const float* __restrict__ shift,
    const int* __restrict__ ei, int E, int* __restrict__ cursor, int* __restrict__ csr_src,
    int gemmBlocks, int N){
  constexpr int K = (LAYER == 0) ? 256 : 64;
  if (LAYER == 0 && (int)blockIdx.x >= gemmBlocks){
    int fb = (int)blockIdx.x - gemmBlocks;
    int xcd = (int)blockIdx.x & 7;          // heuristic round-robin block->XCD
    int grp = fb >> 3;                       // group index within this XCD's set
    int ngrp = ((int)gridDim.x - gemmBlocks) >> 3;
    int nPer = N >> 3;
    int lo = xcd * nPer;
    int hi = (xcd == 7) ? N : lo + nPer;
    int stride = ngrp * 256;
    for (int e = grp * 256 + (int)threadIdx.x; e < E; e += stride){
      int dst = ei[E + e];
      if (dst >= lo && dst < hi){
        int src = ei[e];
        int slot = atomicAdd(&cursor[dst], 1);
        csr_src[slot] = src;
      }
    }
    return;
  }
  __shared__ _Float16 Alds[4][129][8];
  __shared__ _Float16 Blds[4][257][8];
  int tid = threadIdx.x;
  int m0 = blockIdx.x * 128;
  int w = tid >> 6, l = tid & 63;
  int lm = l & 15, lq = l >> 4;
  f32x4 acc[8][4] = {};

  for (int k0 = 0; k0 < K; k0 += 32){
    if (LAYER == 0){
      #pragma unroll
      for (int it = 0; it < 2; it++){
        int gr = m0 + it * 64 + l;
        if (gr < nrows)
          llds16(Xh + (size_t)gr * K + k0 + w * 8, &Alds[w][it * 64][0]);
      }
    } else {
      float4 sc0 = *(const float4*)(scale + k0 + w * 8);
      float4 sc1 = *(const float4*)(scale + k0 + w * 8 + 4);
      float4 sh0 = *(const float4*)(shift + k0 + w * 8);
      float4 sh1 = *(const float4*)(shift + k0 + w * 8 + 4);
      #pragma unroll
      for (int it = 0; it < 2; it++){
        int row = it * 64 + l;
        int gr = m0 + row;
        float4 v0 = make_float4(0,0,0,0), v1 = make_float4(0,0,0,0);
        if (gr < nrows){
          v0 = *(const float4*)(Xf + (size_t)gr * K + k0 + w * 8);
          v1 = *(const float4*)(Xf + (size_t)gr * K + k0 + w * 8 + 4);
        }
        v0.x = fmaxf(fmaf(v0.x, sc0.x, sh0.x), 0.f);
        v0.y = fmaxf(fmaf(v0.y, sc0.y, sh0.y), 0.f);
        v0.z = fmaxf(fmaf(v0.z, sc0.z, sh0.z), 0.f);
        v0.w = fmaxf(fmaf(v0.w, sc0.w, sh0.w), 0.f);
        v1.x = fmaxf(fmaf(v1.x, sc1.x, sh1.x), 0.f);
        v1.y = fmaxf(fmaf(v1.y, sc1.y, sh1.y), 0.f);
        v1.z = fmaxf(fmaf(v1.z, sc1.z, sh1.z), 0.f);
        v1.w = fmaxf(fmaf(v1.w, sc1.w, sh1.w), 0.f);
        half8 h = {(_Float16)v0.x, (_Float16)v0.y, (_Float16)v0.z, (_Float16)v0.w,
                   (_Float16)v1.x, (_Float16)v1.y, (_Float16)v1.z, (_Float16)v1.w};
        *(half8*)&Alds[w][row][0] = h;
      }
    }
    #pragma unroll
    for (int it = 0; it < 4; it++){
      int col = it * 64 + l;
      llds16(Wt + (size_t)col * K + k0 + w * 8, &Blds[w][it * 64][0]);
    }
    __syncthreads();
    half8 af[8];
    #pragma unroll
    for (int mf = 0; mf < 8; mf++) af[mf] = *(const half8*)&Alds[lq][mf * 16 + lm][0];
    #pragma unroll
    for (int j = 0; j < 4; j++){
      half8 bf = *(const half8*)&Blds[lq][(w * 4 + j) * 16 + lm][0];
      #pragma unroll
      for (int mf = 0; mf < 8; mf++)
        acc[mf][j] = __builtin_amdgcn_mfma_f32_16x16x32_f16(af[mf], bf, acc[mf][j], 0, 0, 0);
    }
    __syncthreads();
  }

  float asv[4], adv[4];
  #pragma unroll
  for (int j = 0; j < 4; j++){
    asv[j] = a_s[w * 64 + j * 16 + lm];
    adv[j] = a_d[w * 64 + j * 16 + lm];
  }
  #pragma unroll
  for (int mf = 0; mf < 8; mf++){
    #pragma unroll
    for (int reg = 0; reg < 4; reg++){
      float sl = acc[mf][0][reg] * asv[0] + acc[mf][1][reg] * asv[1]
               + acc[mf][2][reg] * asv[2] + acc[mf][3][reg] * asv[3];
      float sr = acc[mf][0][reg] * adv[0] + acc[mf][1][reg] * adv[1]
               + acc[mf][2][reg] * adv[2] + acc[mf][3][reg] * adv[3];
      #pragma unroll
      for (int off = 1; off < 16; off <<= 1){
        sl += __shfl_xor(sl, off);
        sr += __shfl_xor(sr, off);
      }
      int row = m0 + mf * 16 + lq * 4 + reg;
      if (lm == 0 && row < nrows){
        al[(size_t)row * 4 + w] = sl;
        ar[(size_t)row * 4 + w] = sr;
      }
      if (row < nrows){
        ushort4 pk;
        pk.x = __half_as_ushort(__float2half(acc[mf][0][reg]));
        pk.y = __half_as_ushort(__float2half(acc[mf][1][reg]));
        pk.z = __half_as_ushort(__float2half(acc[mf][2][reg]));
        pk.w = __half_as_ushort(__float2half(acc[mf][3][reg]));
        *(ushort4*)(hb + (size_t)row * 256 + w * 64 + lm * 4) = pk;
      }
    }
  }
}

// ---------------- per-node softmax + aggregate (wave per node) ----------------
__global__ __launch_bounds__(256) void k_node(const int* __restrict__ ptr,
    const int* __restrict__ csr, const __half* __restrict__ hb,
    const float* __restrict__ al, const float* __restrict__ ar,
    const float* __restrict__ bias, float* __restrict__ out, int N){
  __shared__ float4 wsm[4][64];
  __shared__ int    ssm[4][64];
  int n = (blockIdx.x * blockDim.x + threadIdx.x) >> 6;
  int lane = threadIdx.x & 63;
  int wv = threadIdx.x >> 6;
  if (n >= N) return;
  int beg = ptr[n], end = ptr[n + 1];
  int deg = end - beg;
  float4 arv = *(const float4*)(ar + (size_t)n * 4);

  if (deg <= 64){
    int idx = beg + lane;
    bool act = idx < end;
    int mye = act ? csr[idx] : 0;
    float e0 = -1e30f, e1 = -1e30f, e2 = -1e30f, e3 = -1e30f;
    if (act){
      float4 av = *(const float4*)((const char*)al + ((unsigned)mye << 4));
      e0 = lrelu(av.x + arv.x); e1 = lrelu(av.y + arv.y);
      e2 = lrelu(av.z + arv.z); e3 = lrelu(av.w + arv.w);
    }
    float m0 = e0, m1 = e1, m2 = e2, m3 = e3;
    #pragma unroll
    for (int off = 32; off > 0; off >>= 1){
      m0 = fmaxf(m0, __shfl_xor(m0, off));
      m1 = fmaxf(m1, __shfl_xor(m1, off));
      m2 = fmaxf(m2, __shfl_xor(m2, off));
      m3 = fmaxf(m3, __shfl_xor(m3, off));
    }
    float w0 = __expf(e0 - m0), w1 = __expf(e1 - m1);
    float w2 = __expf(e2 - m2), w3 = __expf(e3 - m3);
    float d0 = w0, d1 = w1, d2 = w2, d3 = w3;
    #pragma unroll
    for (int off = 32; off > 0; off >>= 1){
      d0 += __shfl_xor(d0, off);
      d1 += __shfl_xor(d1, off);
      d2 += __shfl_xor(d2, off);
      d3 += __shfl_xor(d3, off);
    }
    wsm[wv][lane] = make_float4(w0 / (d0 + EPS_SM), w1 / (d1 + EPS_SM),
                                w2 / (d2 + EPS_SM), w3 / (d3 + EPS_SM));
    ssm[wv][lane] = mye;
    __builtin_amdgcn_wave_barrier();

    int eh = lane >> 5;
    int hd = (lane >> 3) & 3;
    int c8 = lane & 7;
    unsigned choff = (unsigned)(hd * 128 + c8 * 16);
    const float* wbase = (const float*)&wsm[wv][0];
    float a0=0.f,a1=0.f,a2=0.f,a3=0.f,a4=0.f,a5=0.f,a6=0.f,a7=0.f;
    #pragma unroll 4
    for (int j = 0; j < deg; j += 2){
      int je = j + eh;
      int s = ssm[wv][je];
      float w = wbase[je * 4 + hd];
      int4 q = *(const int4*)((const char*)hb + (((unsigned)s << 9) + choff));
      const __half2* h2 = (const __half2*)&q;
      float2 f0 = __half22float2(h2[0]);
      float2 f1 = __half22float2(h2[1]);
      float2 f2 = __half22float2(h2[2]);
      float2 f3 = __half22float2(h2[3]);
      a0 = fmaf(f0.x, w, a0); a1 = fmaf(f0.y, w, a1);
      a2 = fmaf(f1.x, w, a2); a3 = fmaf(f1.y, w, a3);
      a4 = fmaf(f2.x, w, a4); a5 = fmaf(f2.y, w, a5);
      a6 = fmaf(f3.x, w, a6); a7 = fmaf(f3.y, w, a7);
    }
    #pragma unroll
    for (int off = 32; off >= 8; off >>= 1){
      a0 += __shfl_xor(a0, off); a1 += __shfl_xor(a1, off);
      a2 += __shfl_xor(a2, off); a3 += __shfl_xor(a3, off);
      a4 += __shfl_xor(a4, off); a5 += __shfl_xor(a5, off);
      a6 += __shfl_xor(a6, off); a7 += __shfl_xor(a7, off);
    }
    if (lane < 8){
      float* op = out + (size_t)n * 64 + c8 * 2;
      float2 b0 = *(const float2*)(bias + 0 * 16 + c8 * 2);
      float2 b1 = *(const float2*)(bias + 1 * 16 + c8 * 2);
      float2 b2 = *(const float2*)(bias + 2 * 16 + c8 * 2);
      float2 b3 = *(const float2*)(bias + 3 * 16 + c8 * 2);
      *(float2*)(op + 0)  = make_float2(a0 * 0.25f + b0.x, a4 * 0.25f + b0.y);
      *(float2*)(op + 16) = make_float2(a1 * 0.25f + b1.x, a5 * 0.25f + b1.y);
      *(float2*)(op + 32) = make_float2(a2 * 0.25f + b2.x, a6 * 0.25f + b2.y);
      *(float2*)(op + 48) = make_float2(a3 * 0.25f + b3.x, a7 * 0.25f + b3.y);
    }
  } else {
    int hd = lane >> 4;
    int t = lane & 15;
    const __half* hbase = hb + hd * 64 + t * 4;
    float ax = 0.f, ay = 0.f, az = 0.f, aw = 0.f;
    float m0 = -1e30f, m1 = -1e30f, m2 = -1e30f, m3 = -1e30f;
    for (int i = beg + lane; i < end; i += 64){
      int s = csr[i];
      float4 av = *(const float4*)(al + (size_t)s * 4);
      m0 = fmaxf(m0, lrelu(av.x + arv.x));
      m1 = fmaxf(m1, lrelu(av.y + arv.y));
      m2 = fmaxf(m2, lrelu(av.z + arv.z));
      m3 = fmaxf(m3, lrelu(av.w + arv.w));
    }
    #pragma unroll
    for (int off = 32; off > 0; off >>= 1){
      m0 = fmaxf(m0, __shfl_xor(m0, off));
      m1 = fmaxf(m1, __shfl_xor(m1, off));
      m2 = fmaxf(m2, __shfl_xor(m2, off));
      m3 = fmaxf(m3, __shfl_xor(m3, off));
    }
    float d0 = 0.f, d1 = 0.f, d2 = 0.f, d3 = 0.f;
    for (int i = beg + lane; i < end; i += 64){
      int s = csr[i];
      float4 av = *(const float4*)(al + (size_t)s * 4);
      d0 += __expf(lrelu(av.x + arv.x) - m0);
      d1 += __expf(lrelu(av.y + arv.y) - m1);
      d2 += __expf(lrelu(av.z + arv.z) - m2);
      d3 += __expf(lrelu(av.w + arv.w) - m3);
    }
    #pragma unroll
    for (int off = 32; off > 0; off >>= 1){
      d0 += __shfl_xor(d0, off);
      d1 += __shfl_xor(d1, off);
      d2 += __shfl_xor(d2, off);
      d3 += __shfl_xor(d3, off);
    }
    float i0 = 1.f / (d0 + EPS_SM), i1 = 1.f / (d1 + EPS_SM);
    float i2 = 1.f / (d2 + EPS_SM), i3 = 1.f / (d3 + EPS_SM);
    float arh = hd == 0 ? arv.x : hd == 1 ? arv.y : hd == 2 ? arv.z : arv.w;
    float mh  = hd == 0 ? m0 : hd == 1 ? m1 : hd == 2 ? m2 : m3;
    float ih  = hd == 0 ? i0 : hd == 1 ? i1 : hd == 2 ? i2 : i3;
    for (int i = beg; i < end; i++){
      int s = csr[i];
      float w = __expf(lrelu(al[(size_t)s * 4 + hd] + arh) - mh) * ih;
      ushort4 u = *(const ushort4*)(hbase + (size_t)s * 256);
      ax = fmaf(__half2float(__ushort_as_half(u.x)), w, ax);
      ay = fmaf(__half2float(__ushort_as_half(u.y)), w, ay);
      az = fmaf(__half2float(__ushort_as_half(u.z)), w, az);
      aw = fmaf(__half2float(__ushort_as_half(u.w)), w, aw);
    }
    #pragma unroll
    for (int off = 16; off <= 32; off <<= 1){
      ax += __shfl_xor(ax, off);
      ay += __shfl_xor(ay, off);
      az += __shfl_xor(az, off);
      aw += __shfl_xor(aw, off);
    }
    if (lane < 16){
      float* op = out + (size_t)n * 64;
      op[t]      = ax * 0.25f + bias[t];
      op[16 + t] = ay * 0.25f + bias[16 + t];
      op[32 + t] = az * 0.25f + bias[32 + t];
      op[48 + t] = aw * 0.25f + bias[48 + t];
    }
  }
}

// ---------------- BatchNorm stats + fused finalize -> scale/shift ----------------
__global__ __launch_bounds__(256) void k_bnstats(const float* __restrict__ x, int N,
                                                 float* __restrict__ gsum, float* __restrict__ gsq,
                                                 int* __restrict__ tick,
                                                 const float* __restrict__ g, const float* __restrict__ be,
                                                 float* __restrict__ scale, float* __restrict__ shift){
  int c = threadIdx.x & 63;
  int rg = threadIdx.x >> 6;
  float s = 0.f, q = 0.f;
  for (int r = blockIdx.x * 4 + rg; r < N; r += gridDim.x * 4){
    float v = x[(size_t)r * 64 + c];
    s += v; q += v * v;
  }
  __shared__ float ls[4][64], lq[4][64];
  __shared__ int amLast;
  ls[rg][c] = s; lq[rg][c] = q;
  __syncthreads();
  if (rg == 0){
    s = ls[0][c] + ls[1][c] + ls[2][c] + ls[3][c];
    q = lq[0][c] + lq[1][c] + lq[2][c] + lq[3][c];
    atomicAdd(&gsum[c], s);
    atomicAdd(&gsq[c], q);
  }
  __threadfence();
  if (threadIdx.x == 0)
    amLast = (atomicAdd(tick, 1) == (int)gridDim.x - 1) ? 1 : 0;
  __syncthreads();
  if (amLast && threadIdx.x < 64){
    float gs = atomicAdd(&gsum[c], 0.f);
    float gq = atomicAdd(&gsq[c], 0.f);
    float m = gs / (float)N;
    float v = gq / (float)N - m * m;
    float sc = g[c] * rsqrtf(v + EPS_BN);
    scale[c] = sc;
    shift[c] = be[c] - m * sc;
  }
}

// ---------------- launcher ----------------
extern "C" void kernel_launch(void* const* d_in, const int* in_sizes, int n_in,
                              void* d_out, int out_size, void* d_ws, size_t ws_size,
                              hipStream_t stream){
  const float* x  = (const float*)d_in[0];
  const int*   ei = (const int*)d_in[1];
  const float* W[3]  = {(const float*)d_in[2], (const float*)d_in[6],  (const float*)d_in[10]};
  const float* AS[3] = {(const float*)d_in[3], (const float*)d_in[7],  (const float*)d_in[11]};
  const float* AD[3] = {(const float*)d_in[4], (const float*)d_in[8],  (const float*)d_in[12]};
  const float* BI[3] = {(const float*)d_in[5], (const float*)d_in[9],  (const float*)d_in[13]};
  const float* G[2]  = {(const float*)d_in[14], (const float*)d_in[16]};
  const float* BE[2] = {(const float*)d_in[15], (const float*)d_in[17]};
  const int N = in_sizes[0] / 256;
  const int E = in_sizes[1] / 2;
  const int EN = E + N;

  char* wsb = (char*)d_ws;
  size_t off = 0;
  auto alloc = [&](size_t bytes) -> char* {
    char* p = wsb + off;
    off = (off + bytes + 255) & ~(size_t)255;
    return p;
  };
  int* cnt      = (int*)alloc((size_t)N * 4);
  int* cursor   = (int*)alloc((size_t)N * 4);
  int* rowptr   = (int*)alloc((size_t)(N + 1) * 4);
  int* part     = (int*)alloc(256 * 4);
  int* csr      = (int*)alloc((size_t)EN * 4);
  _Float16* xh  = (_Float16*)alloc((size_t)N * 256 * 2);
  _Float16* Wt0 = (_Float16*)alloc((size_t)256 * 256 * 2);
  _Float16* Wt1 = (_Float16*)alloc((size_t)64 * 256 * 2);
  _Float16* Wt2 = (_Float16*)alloc((size_t)64 * 256 * 2);
  __half* hb    = (__half*)alloc((size_t)N * 256 * 2);
  float* al     = (float*)alloc((size_t)N * 4 * 4);
  float* ar     = (float*)alloc((size_t)N * 4 * 4);
  float* bufA   = (float*)alloc((size_t)N * 64 * 4);
  float* bn     = (float*)alloc(256 * 4);
  int*   tick   = (int*)alloc(4 * 4);
  float* murs   = (float*)alloc(128 * 4);   // scale[64], shift[64]

  const int chunk = (N + 255) / 256;
  const int n8 = N * 32;
  const int nodeGrid = (N + 3) / 4;

  k_prep0<<<(N + 255) / 256, 256, 0, stream>>>(cnt, N, bn, tick);
  k_prep1<<<(n8 + 255) / 256, 256, 0, stream>>>(x, xh, n8, ei, E, cnt,
                                                W[0], W[1], W[2], Wt0, Wt1, Wt2);
  k_bsumscan<<<256, 256, 0, stream>>>(cnt, N, chunk, part, rowptr, tick + 2);
  k_localscan<<<256, 256, 0, stream>>>(cnt, part, N, chunk, rowptr, cursor, csr);

  int gemmGrid = (N + 127) / 128;
  const int FILLB = 512;   // 64 groups x 8 XCD bins
  // layer 0: gemm fused with XCD-binned csr fill
  k_gemm<0><<<gemmGrid + FILLB, 256, 0, stream>>>(xh, nullptr, Wt0, AS[0], AD[0], hb, al, ar, N,
                                                  nullptr, nullptr, ei, E, cursor, csr, gemmGrid, N);
  k_node<<<nodeGrid, 256, 0, stream>>>(rowptr, csr, hb, al, ar, BI[0], bufA, N);
  k_bnstats<<<128, 256, 0, stream>>>(bufA, N, bn, bn + 64, tick, G[0], BE[0], murs, murs + 64);
  // layer 1
  k_gemm<1><<<gemmGrid, 256, 0, stream>>>(nullptr, bufA, Wt1, AS[1], AD[1], hb, al, ar, N,
                                          murs, murs + 64, nullptr, 0, nullptr, nullptr, gemmGrid, N);
  k_node<<<nodeGrid, 256, 0, stream>>>(rowptr, csr, hb, al, ar, BI[1], bufA, N);
  k_bnstats<<<128, 256, 0, stream>>>(bufA, N, bn + 128, bn + 192, tick + 1, G[1], BE[1], murs, murs + 64);
  // layer 2
  k_gemm<2><<<gemmGrid, 256, 0, stream>>>(nullptr, bufA, Wt2, AS[2], AD[2], hb, al, ar, N,
                                          murs, murs + 64, nullptr, 0, nullptr, nullptr, gemmGrid, N);
  k_node<<<nodeGrid, 256, 0, stream>>>(rowptr, csr, hb, al, ar, BI[2], (float*)d_out, N);
}

// Round 16
// 536.851 us; speedup vs baseline: 1.0285x; 1.0109x over previous
//
#include <hip/hip_runtime.h>
#include <hip/hip_fp16.h>
#include <math.h>

constexpr float NEG_SLOPE = 0.2f;
constexpr float EPS_BN = 1e-5f;
constexpr float EPS_SM = 1e-16f;

typedef _Float16 half8 __attribute__((ext_vector_type(8)));
typedef float f32x4 __attribute__((ext_vector_type(4)));

__device__ __forceinline__ float lrelu(float x){ return x >= 0.f ? x : NEG_SLOPE * x; }

typedef const __attribute__((address_space(1))) unsigned int* gas_u32;
typedef __attribute__((address_space(3))) unsigned int* las_u32;

__device__ __forceinline__ void llds16(const _Float16* g, _Float16* l){
  __builtin_amdgcn_global_load_lds((gas_u32)(const void*)g, (las_u32)(void*)l, 16, 0, 0);
}

// ---------------- prep1: x->fp16 + weight fp16-transpose + edge count w/ rank ----------------
__global__ void k_prep1(const float* __restrict__ x, _Float16* __restrict__ xh, int n8,
                        const int* __restrict__ ei, int E, int* __restrict__ cnt,
                        int* __restrict__ rank,
                        const float* __restrict__ W0, const float* __restrict__ W1,
                        const float* __restrict__ W2, _Float16* __restrict__ Wt0,
                        _Float16* __restrict__ Wt1, _Float16* __restrict__ Wt2){
  int t = blockIdx.x * blockDim.x + threadIdx.x;
  if (t < n8){
    const float4* p = (const float4*)(x + (size_t)t * 8);
    float4 v0 = p[0], v1 = p[1];
    half8 h = {(_Float16)v0.x, (_Float16)v0.y, (_Float16)v0.z, (_Float16)v0.w,
               (_Float16)v1.x, (_Float16)v1.y, (_Float16)v1.z, (_Float16)v1.w};
    *(half8*)(xh + (size_t)t * 8) = h;
  }
  if (t < E) rank[t] = atomicAdd(&cnt[ei[E + t]], 1);   // rank among same-dst edges
  if (t < 65536){
    int c = t & 255, k = t >> 8;
    Wt0[(size_t)c * 256 + k] = (_Float16)W0[(size_t)k * 256 + c];
  } else if (t < 81920){
    int u = t - 65536; int c = u & 255, k = u >> 8;
    Wt1[(size_t)c * 64 + k] = (_Float16)W1[(size_t)k * 256 + c];
  } else if (t < 98304){
    int u = t - 81920; int c = u & 255, k = u >> 8;
    Wt2[(size_t)c * 64 + k] = (_Float16)W2[(size_t)k * 256 + c];
  }
}

// ---------------- CSR scans (degree = cnt[i] + 1 for the self-loop) ----------------
__global__ __launch_bounds__(256) void k_bsumscan(const int* __restrict__ cnt, int n, int chunk,
                                                  int* __restrict__ part, int* __restrict__ ptr,
                                                  int* __restrict__ tick){
  __shared__ int s[256];
  __shared__ int amLast;
  int b = blockIdx.x, t = threadIdx.x;
  int lo = b * chunk, hi = min(n, lo + chunk);
  int v = 0;
  for (int i = lo + t; i < hi; i += 256) v += cnt[i] + 1;
  s[t] = v;
  __syncthreads();
  #pragma unroll
  for (int off = 128; off > 0; off >>= 1){
    if (t < off) s[t] += s[t + off];
    __syncthreads();
  }
  if (t == 0) part[b] = s[0];
  __threadfence();
  if (t == 0) amLast = (atomicAdd(tick, 1) == (int)gridDim.x - 1) ? 1 : 0;
  __syncthreads();
  if (amLast){
    int pv = atomicAdd(&part[t], 0);
    s[t] = pv;
    __syncthreads();
    #pragma unroll
    for (int off = 1; off < 256; off <<= 1){
      int u = (t >= off) ? s[t - off] : 0;
      __syncthreads();
      s[t] += u;
      __syncthreads();
    }
    part[t] = s[t] - pv;
    if (t == 255) ptr[n] = s[255];
  }
}

__global__ __launch_bounds__(256) void k_localscan(const int* __restrict__ cnt, const int* __restrict__ part,
                                                   int n, int chunk, int* __restrict__ ptr,
                                                   int* __restrict__ csr_src){
  __shared__ int s[256];
  int b = blockIdx.x, t = threadIdx.x;
  int i = b * chunk + t;
  int c = (t < chunk && i < n) ? cnt[i] : 0;
  int v = (t < chunk && i < n) ? c + 1 : 0;
  s[t] = v;
  __syncthreads();
  #pragma unroll
  for (int off = 1; off < 256; off <<= 1){
    int u = (t >= off) ? s[t - off] : 0;
    __syncthreads();
    s[t] += u;
    __syncthreads();
  }
  if (t < chunk && i < n){
    int ex = part[b] + s[t] - v;
    ptr[i] = ex;
    csr_src[ex + c] = i;     // self-loop after the c ranked edges
  }
}

// ---------------- MFMA GEMM: 128 rows x 256 cols per block; wave w = head w ----------------
// LAYER 0 FUSED with ATOMIC-FREE XCD-BINNED fill: csr[rowptr[dst]+rank[e]] = src.
// hb layout PERMUTED: hb[row][w*64 + lm*4 + j].
template<int LAYER>
__global__ __launch_bounds__(256, 2) void k_gemm(const _Float16* __restrict__ Xh,
    const float* __restrict__ Xf,
    const _Float16* __restrict__ Wt, const float* __restrict__ a_s, const float* __restrict__ a_d,
    __half* __restrict__ hb, float* __restrict__ al, float* __restrict__ ar, int nrows,
    const float* __restrict__ scale, const float* __restrict__ shift,
    const int* __restrict__ ei, int E, const int* __restrict__ rank,
    const int* __restrict__ rowptr, int* __restrict__ csr_src,
    int gemmBlocks, int N){
  constexpr int K = (LAYER == 0) ? 256 : 64;
  if (LAYER == 0 && (int)blockIdx.x >= gemmBlocks){
    int fb = (int)blockIdx.x - gemmBlocks;
    int xcd = (int)blockIdx.x & 7;          // heuristic block->XCD
    int grp = fb >> 3;
    int ngrp = ((int)gridDim.x - gemmBlocks) >> 3;
    int nPer = N >> 3;
    int lo = xcd * nPer;
    int hi = (xcd == 7) ? N : lo + nPer;
    int stride = ngrp * 256;
    for (int e = grp * 256 + (int)threadIdx.x; e < E; e += stride){
      int dst = ei[E + e];
      if (dst >= lo && dst < hi)
        csr_src[rowptr[dst] + rank[e]] = ei[e];   // no atomic
    }
    return;
  }
  __shared__ _Float16 Alds[4][129][8];
  __shared__ _Float16 Blds[4][257][8];
  int tid = threadIdx.x;
  int m0 = blockIdx.x * 128;
  int w = tid >> 6, l = tid & 63;
  int lm = l & 15, lq = l >> 4;
  f32x4 acc[8][4] = {};

  for (int k0 = 0; k0 < K; k0 += 32){
    if (LAYER == 0){
      #pragma unroll
      for (int it = 0; it < 2; it++){
        int gr = m0 + it * 64 + l;
        if (gr < nrows)
          llds16(Xh + (size_t)gr * K + k0 + w * 8, &Alds[w][it * 64][0]);
      }
    } else {
      float4 sc0 = *(const float4*)(scale + k0 + w * 8);
      float4 sc1 = *(const float4*)(scale + k0 + w * 8 + 4);
      float4 sh0 = *(const float4*)(shift + k0 + w * 8);
      float4 sh1 = *(const float4*)(shift + k0 + w * 8 + 4);
      #pragma unroll
      for (int it = 0; it < 2; it++){
        int row = it * 64 + l;
        int gr = m0 + row;
        float4 v0 = make_float4(0,0,0,0), v1 = make_float4(0,0,0,0);
        if (gr < nrows){
          v0 = *(const float4*)(Xf + (size_t)gr * K + k0 + w * 8);
          v1 = *(const float4*)(Xf + (size_t)gr * K + k0 + w * 8 + 4);
        }
        v0.x = fmaxf(fmaf(v0.x, sc0.x, sh0.x), 0.f);
        v0.y = fmaxf(fmaf(v0.y, sc0.y, sh0.y), 0.f);
        v0.z = fmaxf(fmaf(v0.z, sc0.z, sh0.z), 0.f);
        v0.w = fmaxf(fmaf(v0.w, sc0.w, sh0.w), 0.f);
        v1.x = fmaxf(fmaf(v1.x, sc1.x, sh1.x), 0.f);
        v1.y = fmaxf(fmaf(v1.y, sc1.y, sh1.y), 0.f);
        v1.z = fmaxf(fmaf(v1.z, sc1.z, sh1.z), 0.f);
        v1.w = fmaxf(fmaf(v1.w, sc1.w, sh1.w), 0.f);
        half8 h = {(_Float16)v0.x, (_Float16)v0.y, (_Float16)v0.z, (_Float16)v0.w,
                   (_Float16)v1.x, (_Float16)v1.y, (_Float16)v1.z, (_Float16)v1.w};
        *(half8*)&Alds[w][row][0] = h;
      }
    }
    #pragma unroll
    for (int it = 0; it < 4; it++){
      int col = it * 64 + l;
      llds16(Wt + (size_t)col * K + k0 + w * 8, &Blds[w][it * 64][0]);
    }
    __syncthreads();
    half8 af[8];
    #pragma unroll
    for (int mf = 0; mf < 8; mf++) af[mf] = *(const half8*)&Alds[lq][mf * 16 + lm][0];
    #pragma unroll
    for (int j = 0; j < 4; j++){
      half8 bf = *(const half8*)&Blds[lq][(w * 4 + j) * 16 + lm][0];
      #pragma unroll
      for (int mf = 0; mf < 8; mf++)
        acc[mf][j] = __builtin_amdgcn_mfma_f32_16x16x32_f16(af[mf], bf, acc[mf][j], 0, 0, 0);
    }
    __syncthreads();
  }

  float asv[4], adv[4];
  #pragma unroll
  for (int j = 0; j < 4; j++){
    asv[j] = a_s[w * 64 + j * 16 + lm];
    adv[j] = a_d[w * 64 + j * 16 + lm];
  }
  #pragma unroll
  for (int mf = 0; mf < 8; mf++){
    #pragma unroll
    for (int reg = 0; reg < 4; reg++){
      float sl = acc[mf][0][reg] * asv[0] + acc[mf][1][reg] * asv[1]
               + acc[mf][2][reg] * asv[2] + acc[mf][3][reg] * asv[3];
      float sr = acc[mf][0][reg] * adv[0] + acc[mf][1][reg] * adv[1]
               + acc[mf][2][reg] * adv[2] + acc[mf][3][reg] * adv[3];
      #pragma unroll
      for (int off = 1; off < 16; off <<= 1){
        sl += __shfl_xor(sl, off);
        sr += __shfl_xor(sr, off);
      }
      int row = m0 + mf * 16 + lq * 4 + reg;
      if (lm == 0 && row < nrows){
        al[(size_t)row * 4 + w] = sl;
        ar[(size_t)row * 4 + w] = sr;
      }
      if (row < nrows){
        ushort4 pk;
        pk.x = __half_as_ushort(__float2half(acc[mf][0][reg]));
        pk.y = __half_as_ushort(__float2half(acc[mf][1][reg]));
        pk.z = __half_as_ushort(__float2half(acc[mf][2][reg]));
        pk.w = __half_as_ushort(__float2half(acc[mf][3][reg]));
        *(ushort4*)(hb + (size_t)row * 256 + w * 64 + lm * 4) = pk;
      }
    }
  }
}

// ---------------- per-node softmax + aggregate (wave per node) ----------------
__global__ __launch_bounds__(256) void k_node(const int* __restrict__ ptr,
    const int* __restrict__ csr, const __half* __restrict__ hb,
    const float* __restrict__ al, const float* __restrict__ ar,
    const float* __restrict__ bias, float* __restrict__ out, int N){
  __shared__ float4 wsm[4][64];
  __shared__ int    ssm[4][64];
  int n = (blockIdx.x * blockDim.x + threadIdx.x) >> 6;
  int lane = threadIdx.x & 63;
  int wv = threadIdx.x >> 6;
  if (n >= N) return;
  int beg = ptr[n], end = ptr[n + 1];
  int deg = end - beg;
  float4 arv = *(const float4*)(ar + (size_t)n * 4);

  if (deg <= 64){
    int idx = beg + lane;
    bool act = idx < end;
    int mye = act ? csr[idx] : 0;
    float e0 = -1e30f, e1 = -1e30f, e2 = -1e30f, e3 = -1e30f;
    if (act){
      float4 av = *(const float4*)((const char*)al + ((unsigned)mye << 4));
      e0 = lrelu(av.x + arv.x); e1 = lrelu(av.y + arv.y);
      e2 = lrelu(av.z + arv.z); e3 = lrelu(av.w + arv.w);
    }
    float m0 = e0, m1 = e1, m2 = e2, m3 = e3;
    #pragma unroll
    for (int off = 32; off > 0; off >>= 1){
      m0 = fmaxf(m0, __shfl_xor(m0, off));
      m1 = fmaxf(m1, __shfl_xor(m1, off));
      m2 = fmaxf(m2, __shfl_xor(m2, off));
      m3 = fmaxf(m3, __shfl_xor(m3, off));
    }
    float w0 = __expf(e0 - m0), w1 = __expf(e1 - m1);
    float w2 = __expf(e2 - m2), w3 = __expf(e3 - m3);
    float d0 = w0, d1 = w1, d2 = w2, d3 = w3;
    #pragma unroll
    for (int off = 32; off > 0; off >>= 1){
      d0 += __shfl_xor(d0, off);
      d1 += __shfl_xor(d1, off);
      d2 += __shfl_xor(d2, off);
      d3 += __shfl_xor(d3, off);
    }
    wsm[wv][lane] = make_float4(w0 / (d0 + EPS_SM), w1 / (d1 + EPS_SM),
                                w2 / (d2 + EPS_SM), w3 / (d3 + EPS_SM));
    ssm[wv][lane] = mye;
    __builtin_amdgcn_wave_barrier();

    int eh = lane >> 5;
    int hd = (lane >> 3) & 3;
    int c8 = lane & 7;
    unsigned choff = (unsigned)(hd * 128 + c8 * 16);
    const float* wbase = (const float*)&wsm[wv][0];
    float a0=0.f,a1=0.f,a2=0.f,a3=0.f,a4=0.f,a5=0.f,a6=0.f,a7=0.f;
    #pragma unroll 4
    for (int j = 0; j < deg; j += 2){
      int je = j + eh;
      int s = ssm[wv][je];
      float w = wbase[je * 4 + hd];
      int4 q = *(const int4*)((const char*)hb + (((unsigned)s << 9) + choff));
      const __half2* h2 = (const __half2*)&q;
      float2 f0 = __half22float2(h2[0]);
      float2 f1 = __half22float2(h2[1]);
      float2 f2 = __half22float2(h2[2]);
      float2 f3 = __half22float2(h2[3]);
      a0 = fmaf(f0.x, w, a0); a1 = fmaf(f0.y, w, a1);
      a2 = fmaf(f1.x, w, a2); a3 = fmaf(f1.y, w, a3);
      a4 = fmaf(f2.x, w, a4); a5 = fmaf(f2.y, w, a5);
      a6 = fmaf(f3.x, w, a6); a7 = fmaf(f3.y, w, a7);
    }
    #pragma unroll
    for (int off = 32; off >= 8; off >>= 1){
      a0 += __shfl_xor(a0, off); a1 += __shfl_xor(a1, off);
      a2 += __shfl_xor(a2, off); a3 += __shfl_xor(a3, off);
      a4 += __shfl_xor(a4, off); a5 += __shfl_xor(a5, off);
      a6 += __shfl_xor(a6, off); a7 += __shfl_xor(a7, off);
    }
    if (lane < 8){
      float* op = out + (size_t)n * 64 + c8 * 2;
      float2 b0 = *(const float2*)(bias + 0 * 16 + c8 * 2);
      float2 b1 = *(const float2*)(bias + 1 * 16 + c8 * 2);
      float2 b2 = *(const float2*)(bias + 2 * 16 + c8 * 2);
      float2 b3 = *(const float2*)(bias + 3 * 16 + c8 * 2);
      *(float2*)(op + 0)  = make_float2(a0 * 0.25f + b0.x, a4 * 0.25f + b0.y);
      *(float2*)(op + 16) = make_float2(a1 * 0.25f + b1.x, a5 * 0.25f + b1.y);
      *(float2*)(op + 32) = make_float2(a2 * 0.25f + b2.x, a6 * 0.25f + b2.y);
      *(float2*)(op + 48) = make_float2(a3 * 0.25f + b3.x, a7 * 0.25f + b3.y);
    }
  } else {
    int hd = lane >> 4;
    int t = lane & 15;
    const __half* hbase = hb + hd * 64 + t * 4;
    float ax = 0.f, ay = 0.f, az = 0.f, aw = 0.f;
    float m0 = -1e30f, m1 = -1e30f, m2 = -1e30f, m3 = -1e30f;
    for (int i = beg + lane; i < end; i += 64){
      int s = csr[i];
      float4 av = *(const float4*)(al + (size_t)s * 4);
      m0 = fmaxf(m0, lrelu(av.x + arv.x));
      m1 = fmaxf(m1, lrelu(av.y + arv.y));
      m2 = fmaxf(m2, lrelu(av.z + arv.z));
      m3 = fmaxf(m3, lrelu(av.w + arv.w));
    }
    #pragma unroll
    for (int off = 32; off > 0; off >>= 1){
      m0 = fmaxf(m0, __shfl_xor(m0, off));
      m1 = fmaxf(m1, __shfl_xor(m1, off));
      m2 = fmaxf(m2, __shfl_xor(m2, off));
      m3 = fmaxf(m3, __shfl_xor(m3, off));
    }
    float d0 = 0.f, d1 = 0.f, d2 = 0.f, d3 = 0.f;
    for (int i = beg + lane; i < end; i += 64){
      int s = csr[i];
      float4 av = *(const float4*)(al + (size_t)s * 4);
      d0 += __expf(lrelu(av.x + arv.x) - m0);
      d1 += __expf(lrelu(av.y + arv.y) - m1);
      d2 += __expf(lrelu(av.z + arv.z) - m2);
      d3 += __expf(lrelu(av.w + arv.w) - m3);
    }
    #pragma unroll
    for (int off = 32; off > 0; off >>= 1){
      d0 += __shfl_xor(d0, off);
      d1 += __shfl_xor(d1, off);
      d2 += __shfl_xor(d2, off);
      d3 += __shfl_xor(d3, off);
    }
    float i0 = 1.f / (d0 + EPS_SM), i1 = 1.f / (d1 + EPS_SM);
    float i2 = 1.f / (d2 + EPS_SM), i3 = 1.f / (d3 + EPS_SM);
    float arh = hd == 0 ? arv.x : hd == 1 ? arv.y : hd == 2 ? arv.z : arv.w;
    float mh  = hd == 0 ? m0 : hd == 1 ? m1 : hd == 2 ? m2 : m3;
    float ih  = hd == 0 ? i0 : hd == 1 ? i1 : hd == 2 ? i2 : i3;
    for (int i = beg; i < end; i++){
      int s = csr[i];
      float w = __expf(lrelu(al[(size_t)s * 4 + hd] + arh) - mh) * ih;
      ushort4 u = *(const ushort4*)(hbase + (size_t)s * 256);
      ax = fmaf(__half2float(__ushort_as_half(u.x)), w, ax);
      ay = fmaf(__half2float(__ushort_as_half(u.y)), w, ay);
      az = fmaf(__half2float(__ushort_as_half(u.z)), w, az);
      aw = fmaf(__half2float(__ushort_as_half(u.w)), w, aw);
    }
    #pragma unroll
    for (int off = 16; off <= 32; off <<= 1){
      ax += __shfl_xor(ax, off);
      ay += __shfl_xor(ay, off);
      az += __shfl_xor(az, off);
      aw += __shfl_xor(aw, off);
    }
    if (lane < 16){
      float* op = out + (size_t)n * 64;
      op[t]      = ax * 0.25f + bias[t];
      op[16 + t] = ay * 0.25f + bias[16 + t];
      op[32 + t] = az * 0.25f + bias[32 + t];
      op[48 + t] = aw * 0.25f + bias[48 + t];
    }
  }
}

// ---------------- BatchNorm stats + fused finalize -> scale/shift ----------------
__global__ __launch_bounds__(256) void k_bnstats(const float* __restrict__ x, int N,
                                                 float* __restrict__ gsum, float* __restrict__ gsq,
                                                 int* __restrict__ tick,
                                                 const float* __restrict__ g, const float* __restrict__ be,
                                                 float* __restrict__ scale, float* __restrict__ shift){
  int c = threadIdx.x & 63;
  int rg = threadIdx.x >> 6;
  float s = 0.f, q = 0.f;
  for (int r = blockIdx.x * 4 + rg; r < N; r += gridDim.x * 4){
    float v = x[(size_t)r * 64 + c];
    s += v; q += v * v;
  }
  __shared__ float ls[4][64], lq[4][64];
  __shared__ int amLast;
  ls[rg][c] = s; lq[rg][c] = q;
  __syncthreads();
  if (rg == 0){
    s = ls[0][c] + ls[1][c] + ls[2][c] + ls[3][c];
    q = lq[0][c] + lq[1][c] + lq[2][c] + lq[3][c];
    atomicAdd(&gsum[c], s);
    atomicAdd(&gsq[c], q);
  }
  __threadfence();
  if (threadIdx.x == 0)
    amLast = (atomicAdd(tick, 1) == (int)gridDim.x - 1) ? 1 : 0;
  __syncthreads();
  if (amLast && threadIdx.x < 64){
    float gs = atomicAdd(&gsum[c], 0.f);
    float gq = atomicAdd(&gsq[c], 0.f);
    float m = gs / (float)N;
    float v = gq / (float)N - m * m;
    float sc = g[c] * rsqrtf(v + EPS_BN);
    scale[c] = sc;
    shift[c] = be[c] - m * sc;
  }
}

// ---------------- launcher ----------------
extern "C" void kernel_launch(void* const* d_in, const int* in_sizes, int n_in,
                              void* d_out, int out_size, void* d_ws, size_t ws_size,
                              hipStream_t stream){
  const float* x  = (const float*)d_in[0];
  const int*   ei = (const int*)d_in[1];
  const float* W[3]  = {(const float*)d_in[2], (const float*)d_in[6],  (const float*)d_in[10]};
  const float* AS[3] = {(const float*)d_in[3], (const float*)d_in[7],  (const float*)d_in[11]};
  const float* AD[3] = {(const float*)d_in[4], (const float*)d_in[8],  (const float*)d_in[12]};
  const float* BI[3] = {(const float*)d_in[5], (const float*)d_in[9],  (const float*)d_in[13]};
  const float* G[2]  = {(const float*)d_in[14], (const float*)d_in[16]};
  const float* BE[2] = {(const float*)d_in[15], (const float*)d_in[17]};
  const int N = in_sizes[0] / 256;
  const int E = in_sizes[1] / 2;
  const int EN = E + N;

  char* wsb = (char*)d_ws;
  size_t off = 0;
  auto alloc = [&](size_t bytes) -> char* {
    char* p = wsb + off;
    off = (off + bytes + 255) & ~(size_t)255;
    return p;
  };
  int* cnt      = (int*)alloc((size_t)N * 4);
  int* rowptr   = (int*)alloc((size_t)(N + 1) * 4);
  int* part     = (int*)alloc(256 * 4);
  int* rank     = (int*)alloc((size_t)E * 4);
  int* csr      = (int*)alloc((size_t)EN * 4);
  _Float16* xh  = (_Float16*)alloc((size_t)N * 256 * 2);
  _Float16* Wt0 = (_Float16*)alloc((size_t)256 * 256 * 2);
  _Float16* Wt1 = (_Float16*)alloc((size_t)64 * 256 * 2);
  _Float16* Wt2 = (_Float16*)alloc((size_t)64 * 256 * 2);
  __half* hb    = (__half*)alloc((size_t)N * 256 * 2);
  float* al     = (float*)alloc((size_t)N * 4 * 4);
  float* ar     = (float*)alloc((size_t)N * 4 * 4);
  float* bufA   = (float*)alloc((size_t)N * 64 * 4);
  float* bn     = (float*)alloc(256 * 4);
  int*   tick   = (int*)alloc(4 * 4);
  float* murs   = (float*)alloc(128 * 4);   // scale[64], shift[64]

  const int chunk = (N + 255) / 256;
  const int n8 = N * 32;
  const int nodeGrid = (N + 3) / 4;

  hipMemsetAsync(cnt, 0, (size_t)N * 4, stream);
  hipMemsetAsync(bn, 0, 256 * 4, stream);
  hipMemsetAsync(tick, 0, 4 * 4, stream);
  k_prep1<<<(n8 + 255) / 256, 256, 0, stream>>>(x, xh, n8, ei, E, cnt, rank,
                                                W[0], W[1], W[2], Wt0, Wt1, Wt2);
  k_bsumscan<<<256, 256, 0, stream>>>(cnt, N, chunk, part, rowptr, tick + 2);
  k_localscan<<<256, 256, 0, stream>>>(cnt, part, N, chunk, rowptr, csr);

  int gemmGrid = (N + 127) / 128;
  const int FILLB = 1024;   // 128 groups x 8 XCD bins, atomic-free scatter
  // layer 0: gemm fused with atomic-free XCD-binned csr fill
  k_gemm<0><<<gemmGrid + FILLB, 256, 0, stream>>>(xh, nullptr, Wt0, AS[0], AD[0], hb, al, ar, N,
                                                  nullptr, nullptr, ei, E, rank, rowptr, csr,
                                                  gemmGrid, N);
  k_node<<<nodeGrid, 256, 0, stream>>>(rowptr, csr, hb, al, ar, BI[0], bufA, N);
  k_bnstats<<<128, 256, 0, stream>>>(bufA, N, bn, bn + 64, tick, G[0], BE[0], murs, murs + 64);
  // layer 1
  k_gemm<1><<<gemmGrid, 256, 0, stream>>>(nullptr, bufA, Wt1, AS[1], AD[1], hb, al, ar, N,
                                          murs, murs + 64, nullptr, 0, nullptr, nullptr, nullptr,
                                          gemmGrid, N);
  k_node<<<nodeGrid, 256, 0, stream>>>(rowptr, csr, hb, al, ar, BI[1], bufA, N);
  k_bnstats<<<128, 256, 0, stream>>>(bufA, N, bn + 128, bn + 192, tick + 1, G[1], BE[1], murs, murs + 64);
  // layer 2
  k_gemm<2><<<gemmGrid, 256, 0, stream>>>(nullptr, bufA, Wt2, AS[2], AD[2], hb, al, ar, N,
                                          murs, murs + 64, nullptr, 0, nullptr, nullptr, nullptr,
                                          gemmGrid, N);
  k_node<<<nodeGrid, 256, 0, stream>>>(rowptr, csr, hb, al, ar, BI[2], (float*)d_out, N);
}